// Round 2
// baseline (253.047 us; speedup 1.0000x reference)
//
#include <hip/hip_runtime.h>
#include <hip/hip_bf16.h>

typedef float f32x4 __attribute__((ext_vector_type(4)));
typedef short s16x8 __attribute__((ext_vector_type(8)));

using bf16 = __hip_bfloat16;

namespace {
constexpr int KD = 1024;            // 8 * C_IN
constexpr int BM = 128;
constexpr int BK = 32;
constexpr int NT = KD / BK;         // 32 K-tiles
constexpr int MBLK = 131072 / BM;   // 1024 GEMM blocks
constexpr int ZBLK = 1024;          // zero-fill blocks appended to the grid
}

typedef __attribute__((address_space(1))) const void GVoid;
typedef __attribute__((address_space(3))) void LVoid;

// async global->LDS, 16B per lane; LDS dest = wave-uniform base + lane*16
__device__ __forceinline__ void gld16(const void* g, void* l) {
  __builtin_amdgcn_global_load_lds((GVoid*)g, (LVoid*)l, 16, 0, 0);
}

__device__ __forceinline__ s16x8 cvt8(f32x4 a, f32x4 b) {
  union { s16x8 v; bf16 h[8]; } u;
#pragma unroll
  for (int j = 0; j < 4; ++j) u.h[j] = __float2bfloat16(a[j]);
#pragma unroll
  for (int j = 0; j < 4; ++j) u.h[j + 4] = __float2bfloat16(b[j]);
  return u.v;
}

// weights [1024][256] fp32 -> Bt [256][1024] bf16 (transposed, MFMA-B friendly)
__global__ void k_transpose_w(const float* __restrict__ w, bf16* __restrict__ bt) {
  int t = blockIdx.x * 256 + threadIdx.x;   // 32768 threads
  int n = t & 255;
  int k0 = (t >> 8) << 3;
  union { s16x8 v; bf16 h[8]; } u;
#pragma unroll
  for (int j = 0; j < 8; ++j)
    u.h[j] = __float2bfloat16(w[(size_t)(k0 + j) * 256 + n]);
  *(s16x8*)(bt + (size_t)n * KD + k0) = u.v;
}

__global__ void k_clear_flags(int* __restrict__ flags, int np4) {
  int i = blockIdx.x * 256 + threadIdx.x;
  if (i < np4) ((int4*)flags)[i] = make_int4(0, 0, 0, 0);
}

__global__ void k_set_flags(const int* __restrict__ idx, int* __restrict__ flags, int m) {
  int i = blockIdx.x * 256 + threadIdx.x;
  if (i < m) flags[idx[i]] = 1;
}

// Fused: blocks [0, MBLK) do the MFMA GEMM with scatter-store epilogue;
// blocks [MBLK, MBLK+ZBLK) zero the empty parent rows (overlaps GEMM tail).
// A staged fp32 via global_load_lds (swizzled source, linear dest), cvt->bf16
// at fragment read. B pre-transposed bf16, also global_load_lds-staged.
__global__ __launch_bounds__(512, 4)
void k_fused(const float* __restrict__ A, const bf16* __restrict__ Bt,
             const int* __restrict__ idx, const int* __restrict__ flags,
             float* __restrict__ out, int NP) {
  __shared__ float As[2][BM * BK];    // 2 x 16 KB fp32
  __shared__ bf16  Bs[2][256 * BK];   // 2 x 16 KB bf16

  const int tid = threadIdx.x;
  const int lane = tid & 63;
  const int wave = tid >> 6;          // 0..7

  if (blockIdx.x >= MBLK) {           // ---- zero-fill path ----
    const int zb = blockIdx.x - MBLK;
    f32x4 z = {0.f, 0.f, 0.f, 0.f};
    for (int row = zb * 8 + wave; row < NP; row += ZBLK * 8) {
      if (flags[row] == 0)
        *(f32x4*)(out + (size_t)row * 256 + lane * 4) = z;
    }
    return;
  }

  // ---- GEMM path ----
  const int m0 = blockIdx.x * BM;
  const int wm = wave >> 2;           // 0..1 (row half)
  const int wn = wave & 3;            // 0..3 (col quarter)

  // Staging: LDS filled LINEARLY in 16B chunks (gld16 requirement); the
  // swizzle lives in the per-lane GLOBAL source address (rule #21).
  // A: 1024 chunks (row stride 8), swizzle c^(row&6) (pair-aligned).
  const int as0 = tid, as1 = 512 + tid;
  const int ar0 = as0 >> 3, ac0 = (as0 & 7) ^ (ar0 & 6);
  const int ar1 = as1 >> 3, ac1 = (as1 & 7) ^ (ar1 & 6);
  const float* aSrc0 = A + (size_t)(m0 + ar0) * KD + ac0 * 4;
  const float* aSrc1 = A + (size_t)(m0 + ar1) * KD + ac1 * 4;
  const int aOff0 = (wave * 64) * 4;          // f32 index of wave's chunk run
  const int aOff1 = (512 + wave * 64) * 4;

  // B: 1024 chunks (row stride 4), swizzle c^(row&3).
  const int bs0 = tid, bs1 = 512 + tid;
  const int br0 = bs0 >> 2, bc0 = (bs0 & 3) ^ (br0 & 3);
  const int br1 = bs1 >> 2, bc1 = (bs1 & 3) ^ (br1 & 3);
  const bf16* bSrc0 = Bt + (size_t)br0 * KD + bc0 * 8;
  const bf16* bSrc1 = Bt + (size_t)br1 * KD + bc1 * 8;
  const int bOff0 = (wave * 64) * 8;          // bf16 index
  const int bOff1 = (512 + wave * 64) * 8;

  // Fragment read offsets (16x16x32: lane -> row l&15, k-octet l>>4), with
  // the SAME swizzle applied on the read side. fm/fn stride 16 rows = 512
  // elements; (row+16)&swz_mask unchanged, so the stride is constant.
  const int arow = wm * 64 + (lane & 15);
  const int kc = lane >> 4;
  const int aRd = arow * 32 + (((2 * kc) ^ (arow & 6)) * 4);  // f32 idx
  const int brow = wn * 64 + (lane & 15);
  const int bRd = brow * 32 + ((kc ^ (brow & 3)) * 8);        // bf16 idx

  f32x4 acc[4][4] = {};

  auto stage = [&](int buf, int t) {
    gld16(aSrc0 + t * BK, &As[buf][aOff0]);
    gld16(aSrc1 + t * BK, &As[buf][aOff1]);
    gld16(bSrc0 + t * BK, &Bs[buf][bOff0]);
    gld16(bSrc1 + t * BK, &Bs[buf][bOff1]);
  };

  stage(0, 0);
  __syncthreads();   // compiler emits vmcnt(0) drain before s_barrier

  int cur = 0;
#pragma unroll 1
  for (int t = 0; t < NT; ++t) {
    if (t + 1 < NT) stage(cur ^ 1, t + 1);   // issue async loads first

    s16x8 bfr[4];
#pragma unroll
    for (int fn = 0; fn < 4; ++fn)
      bfr[fn] = *(const s16x8*)(&Bs[cur][bRd + fn * 512]);

#pragma unroll
    for (int fm = 0; fm < 4; ++fm) {
      f32x4 lo = *(const f32x4*)(&As[cur][aRd + fm * 512]);
      f32x4 hi = *(const f32x4*)(&As[cur][aRd + fm * 512 + 4]);
      s16x8 af = cvt8(lo, hi);
#pragma unroll
      for (int fn = 0; fn < 4; ++fn)
        acc[fm][fn] = __builtin_amdgcn_mfma_f32_16x16x32_bf16(
            af, bfr[fn], acc[fm][fn], 0, 0, 0);
    }
    __syncthreads();
    cur ^= 1;
  }

  // ---- epilogue: C/D layout col = lane&15, row = (lane>>4)*4 + j ----
  const int col0 = wn * 64 + (lane & 15);
  const int rb = m0 + wm * 64 + ((lane >> 4) << 2);
#pragma unroll
  for (int fm = 0; fm < 4; ++fm) {
#pragma unroll
    for (int j = 0; j < 4; ++j) {
      int orow = idx[rb + fm * 16 + j];
      float* op = out + (size_t)orow * 256 + col0;
#pragma unroll
      for (int fn = 0; fn < 4; ++fn)
        op[fn * 16] = acc[fm][fn][j];
    }
  }
}

extern "C" void kernel_launch(void* const* d_in, const int* in_sizes, int n_in,
                              void* d_out, int out_size, void* d_ws, size_t ws_size,
                              hipStream_t stream) {
  const float* data = (const float*)d_in[0];   // [N, 128] == [M, 1024]
  const float* w    = (const float*)d_in[1];   // [8,128,256] == [1024, 256]
  const int*   idx  = (const int*)d_in[2];     // [M] sorted unique parent slots
  float* out = (float*)d_out;                  // [NP, 256]

  const int M  = in_sizes[2];        // 131072
  const int NP = out_size / 256;     // 262144

  int* flags = (int*)d_ws;                                    // NP ints (1 MB)
  bf16* bt = (bf16*)((char*)d_ws + (size_t)NP * sizeof(int)); // 512 KB

  k_transpose_w<<<128, 256, 0, stream>>>(w, bt);
  k_clear_flags<<<(NP / 4 + 255) / 256, 256, 0, stream>>>(flags, NP / 4);
  k_set_flags<<<(M + 255) / 256, 256, 0, stream>>>(idx, flags, M);
  k_fused<<<MBLK + ZBLK, 512, 0, stream>>>(data, bt, idx, flags, out, NP);
}